// Round 9
// baseline (125.688 us; speedup 1.0000x reference)
//
#include <hip/hip_runtime.h>
#include <hip/hip_bf16.h>
#include <math.h>

#define BB 4
#define LL 4096
#define DD 512
#define DF 1024
#define CHUNKS 64
#define LC 64  // LL / CHUNKS
#define HALF_ROWS 8192

typedef __bf16 bf16x8 __attribute__((ext_vector_type(8)));
typedef float f32x4 __attribute__((ext_vector_type(4)));

// ---------------- phazor helper ----------------
__device__ inline void get_phazor(const float* __restrict__ pre, const float* __restrict__ pim,
                                  int d, float& ar, float& ai) {
    float pr = pre[d], pi = pim[d];
    float ab = sqrtf(pr * pr + pi * pi);
    float sc = expf(-ab) / ab;
    ar = pr * sc;
    ai = pi * sc;
}

// ---------------- kernel W: coalesced 32x32 tiled transpose f32 -> bf16 ----------------
__global__ __launch_bounds__(256) void k_wt(const float* __restrict__ w1, const float* __restrict__ w2,
                                            __bf16* __restrict__ w1t, __bf16* __restrict__ w2t) {
    __shared__ float tile[32][33];
    const float* src;
    __bf16* dst;
    int R, C;
    if (blockIdx.y == 0) { src = w1; dst = w1t; R = DD; C = DF; }
    else                 { src = w2; dst = w2t; R = DF; C = DD; }
    int ntx = C / 32;
    int c0 = (blockIdx.x % ntx) * 32, r0 = (blockIdx.x / ntx) * 32;
    int tx = threadIdx.x & 31, ty = threadIdx.x >> 5;  // ty in 0..7
#pragma unroll
    for (int i = 0; i < 32; i += 8)
        tile[ty + i][tx] = src[(size_t)(r0 + ty + i) * C + c0 + tx];
    __syncthreads();
#pragma unroll
    for (int i = 0; i < 32; i += 8)
        dst[(size_t)(c0 + ty + i) * R + r0 + tx] = (__bf16)tile[tx][ty + i];
}

// ---------------- kernel A: x row stats ----------------
__global__ __launch_bounds__(256) void k_xstats(const float* __restrict__ x, float* __restrict__ xstats) {
    int wave = threadIdx.x >> 6, lane = threadIdx.x & 63;
    size_t row = (size_t)blockIdx.x * 4 + wave;  // 16384 rows
    const float4* xr = reinterpret_cast<const float4*>(x + row * DD) + lane * 2;
    float4 a = xr[0], b = xr[1];
    float s = a.x + a.y + a.z + a.w + b.x + b.y + b.z + b.w;
    float q = a.x * a.x + a.y * a.y + a.z * a.z + a.w * a.w +
              b.x * b.x + b.y * b.y + b.z * b.z + b.w * b.w;
#pragma unroll
    for (int off = 32; off; off >>= 1) {
        s += __shfl_down(s, off);
        q += __shfl_down(q, off);
    }
    if (lane == 0) {
        float m = s * (1.0f / DD);
        float v = q * (1.0f / DD) - m * m;
        xstats[row * 2 + 0] = m;
        xstats[row * 2 + 1] = rsqrtf(v + 1e-5f);
    }
}

// ---------------- kernel B: per-chunk partial scan (zero init) ----------------
__global__ __launch_bounds__(512) void k_scan_partial(
    const float* __restrict__ x, const float* __restrict__ xstats,
    const float* __restrict__ pre, const float* __restrict__ pim,
    const float* __restrict__ pinr, const float* __restrict__ pini,
    const float* __restrict__ g, const float* __restrict__ bvec,
    float* __restrict__ carry) {
    int d = threadIdx.x;
    int c = blockIdx.x % CHUNKS, b = blockIdx.x / CHUNKS;
    float ar, ai;
    get_phazor(pre, pim, d, ar, ai);
    float pr = pinr[d], pi = pini[d];
    float gd = g[d], bd = bvec[d];
    float hr = 0.f, hi = 0.f;
    int l0 = c * LC;
    const float* xp = x + ((size_t)b * LL + l0) * DD + d;
    const float* st = xstats + ((size_t)b * LL + l0) * 2;
    for (int i = 0; i < LC; i++) {
        float m = st[2 * i], r = st[2 * i + 1];
        float xn = (xp[(size_t)i * DD] - m) * r * gd + bd;
        float ur = pr * xn, ui = pi * xn;
        float t = ar * hr - ai * hi + ur;
        hi = ar * hi + ai * hr + ui;
        hr = t;
    }
    size_t idx = ((size_t)blockIdx.x * DD + d) * 2;
    carry[idx] = hr;
    carry[idx + 1] = hi;
}

// ---------------- kernel C: cross-chunk scan ----------------
__global__ __launch_bounds__(512) void k_chunk_scan(
    const float* __restrict__ hr0, const float* __restrict__ hi0,
    const float* __restrict__ pre, const float* __restrict__ pim,
    const float* __restrict__ carry, float* __restrict__ carry_in) {
    int d = threadIdx.x, b = blockIdx.x;
    float ar, ai;
    get_phazor(pre, pim, d, ar, ai);
    float sr = ar, si = ai;  // a^64 via 6 squarings
#pragma unroll
    for (int i = 0; i < 6; i++) {
        float t = sr * sr - si * si;
        si = 2.f * sr * si;
        sr = t;
    }
    float cr = hr0[b * DD + d], ci = hi0[b * DD + d];
    for (int k = 0; k < CHUNKS; k++) {
        size_t idx = (((size_t)b * CHUNKS + k) * DD + d) * 2;
        carry_in[idx] = cr;
        carry_in[idx + 1] = ci;
        float tr = carry[idx], ti = carry[idx + 1];
        float t = sr * cr - si * ci + tr;
        ci = sr * ci + si * cr + ti;
        cr = t;
    }
}

// ---------------- kernel D: final scan.
// MODE 0: y only. MODE 1: hidden real only. MODE 2: hidden interleaved only. MODE 3: y + hidden real.
template <int MODE>
__global__ __launch_bounds__(512) void k_scan_out(
    const float* __restrict__ x, const float* __restrict__ xstats,
    const float* __restrict__ pre, const float* __restrict__ pim,
    const float* __restrict__ pinr, const float* __restrict__ pini,
    const float* __restrict__ g, const float* __restrict__ bvec,
    const float* __restrict__ carry_in,
    float* __restrict__ out_y, float* __restrict__ hid) {
    int d = threadIdx.x;
    int c = blockIdx.x % CHUNKS, b = blockIdx.x / CHUNKS;
    float ar, ai;
    get_phazor(pre, pim, d, ar, ai);
    float pr = pinr[d], pi = pini[d];
    float gd = g[d], bd = bvec[d];
    size_t cidx = ((size_t)blockIdx.x * DD + d) * 2;
    float hr = carry_in[cidx], hi = carry_in[cidx + 1];
    int l0 = c * LC;
    const float* xp = x + ((size_t)b * LL + l0) * DD + d;
    const float* st = xstats + ((size_t)b * LL + l0) * 2;
    for (int i = 0; i < LC; i++) {
        float m = st[2 * i], r = st[2 * i + 1];
        float xv = xp[(size_t)i * DD];
        float xn = (xv - m) * r * gd + bd;
        float ur = pr * xn, ui = pi * xn;
        float t = ar * hr - ai * hi + ur;
        hi = ar * hi + ai * hr + ui;
        hr = t;
        size_t row = (size_t)b * LL + l0 + i;
        if constexpr (MODE == 0) {
            out_y[row * DD + d] = hr + xv;
        } else if constexpr (MODE == 1) {
            hid[row * DD + d] = hr;
        } else if constexpr (MODE == 2) {
            reinterpret_cast<float2*>(hid)[row * DD + d] = make_float2(hr, hi);
        } else {
            out_y[row * DD + d] = hr + xv;
            hid[row * DD + d] = hr;
        }
    }
}

// ---------------- kernel E: y -> yn (bf16 normalized) ----------------
__global__ __launch_bounds__(256) void k_ynorm(const float* __restrict__ y,
                                               const float* __restrict__ g, const float* __restrict__ bvec,
                                               __bf16* __restrict__ yn) {
    int wave = threadIdx.x >> 6, lane = threadIdx.x & 63;
    size_t row = (size_t)blockIdx.x * 4 + wave;
    const float4* yr = reinterpret_cast<const float4*>(y + row * DD) + lane * 2;
    float4 a = yr[0], b = yr[1];
    float s = a.x + a.y + a.z + a.w + b.x + b.y + b.z + b.w;
    float q = a.x * a.x + a.y * a.y + a.z * a.z + a.w * a.w +
              b.x * b.x + b.y * b.y + b.z * b.z + b.w * b.w;
#pragma unroll
    for (int off = 32; off; off >>= 1) {
        s += __shfl_xor(s, off);
        q += __shfl_xor(q, off);
    }
    float m = s * (1.0f / DD);
    float r = rsqrtf(q * (1.0f / DD) - m * m + 1e-5f);
    int dbase = lane * 8;
    const float4* gp = reinterpret_cast<const float4*>(g + dbase);
    const float4* bp = reinterpret_cast<const float4*>(bvec + dbase);
    float4 g0 = gp[0], g1 = gp[1], b0 = bp[0], b1 = bp[1];
    bf16x8 o;
    o[0] = (__bf16)((a.x - m) * r * g0.x + b0.x);
    o[1] = (__bf16)((a.y - m) * r * g0.y + b0.y);
    o[2] = (__bf16)((a.z - m) * r * g0.z + b0.z);
    o[3] = (__bf16)((a.w - m) * r * g0.w + b0.w);
    o[4] = (__bf16)((b.x - m) * r * g1.x + b1.x);
    o[5] = (__bf16)((b.y - m) * r * g1.y + b1.y);
    o[6] = (__bf16)((b.z - m) * r * g1.z + b1.z);
    o[7] = (__bf16)((b.w - m) * r * g1.w + b1.w);
    *reinterpret_cast<bf16x8*>(yn + row * DD + dbase) = o;
}

// ---------------- GEMM: 2-phase double-buffered (stage next || compute cur) ----------------
// C[m][n] = A[m][:].Bt[n][:] ; EPI 1: out_bf16 = silu(acc+bias). EPI 2: out_f32 = acc+bias+yadd.
// LDS 2 x [128][64] bf16 per operand; linear gload_lds dest; XOR-swizzle on 16B chunk
// column vs (row&7), applied on global source AND ds_read (both-sides, rule 21).
// One __syncthreads per K-step (compiler drains vmcnt+lgkm before s_barrier).
template <int KDIM, int NDIM, int EPI>
__global__ __launch_bounds__(256) void k_gemm(
    const __bf16* __restrict__ A, const __bf16* __restrict__ Bt,
    const float* __restrict__ bias, const float* __restrict__ yadd,
    float* __restrict__ outf, __bf16* __restrict__ outb) {
    __shared__ __align__(16) __bf16 As[2][128 * 64];
    __shared__ __align__(16) __bf16 Bs[2][128 * 64];
    constexpr int NT = NDIM / 128;
    int nwg = gridDim.x;
    int bid = blockIdx.x;
    int swz = (bid & 7) * (nwg >> 3) + (bid >> 3);
    int m0 = (swz / NT) * 128;
    int n0 = (swz % NT) * 128;
    int tid = threadIdx.x;
    int wave = tid >> 6, lane = tid & 63;

    f32x4 acc[4][4] = {};

    int wm = (wave & 1) * 64, wn = (wave >> 1) * 64;
    int fr = lane & 15;         // fragment row within 16
    int qbase = lane >> 4;      // 16B-chunk quarter within 32 cols

    // Per-thread staging geometry (constant across K-steps)
    int c_ = tid;               // chunk base; chunks c_, c_+256, c_+512, c_+768

#define STAGE(buf, k0)                                                                              \
    {                                                                                               \
        _Pragma("unroll")                                                                           \
        for (int i = 0; i < 4; i++) {                                                               \
            int c = c_ + i * 256;                                                                   \
            int row = c >> 3, kq = c & 7;                                                           \
            int kqg = kq ^ (row & 7);                                                               \
            const __bf16* ga = A + (size_t)(m0 + row) * KDIM + (k0) + kqg * 8;                      \
            const __bf16* gb = Bt + (size_t)(n0 + row) * KDIM + (k0) + kqg * 8;                     \
            __bf16* la = &As[buf][(size_t)(i * 256 + wave * 64) * 8];                               \
            __bf16* lb = &Bs[buf][(size_t)(i * 256 + wave * 64) * 8];                               \
            __builtin_amdgcn_global_load_lds((const __attribute__((address_space(1))) unsigned int*)ga, \
                                             (__attribute__((address_space(3))) unsigned int*)la, 16, 0, 0); \
            __builtin_amdgcn_global_load_lds((const __attribute__((address_space(1))) unsigned int*)gb, \
                                             (__attribute__((address_space(3))) unsigned int*)lb, 16, 0, 0); \
        }                                                                                           \
    }

#define COMPUTE(buf)                                                                                \
    {                                                                                               \
        _Pragma("unroll")                                                                           \
        for (int ks = 0; ks < 2; ks++) {                                                            \
            int q = ks * 4 + qbase;                                                                 \
            bf16x8 af[4], bfv[4];                                                                   \
            _Pragma("unroll")                                                                       \
            for (int mi = 0; mi < 4; mi++) {                                                        \
                int R = wm + mi * 16 + fr;                                                          \
                af[mi] = *reinterpret_cast<const bf16x8*>(&As[buf][R * 64 + ((q ^ (R & 7)) << 3)]); \
            }                                                                                       \
            _Pragma("unroll")                                                                       \
            for (int ni = 0; ni < 4; ni++) {                                                        \
                int R = wn + ni * 16 + fr;                                                          \
                bfv[ni] = *reinterpret_cast<const bf16x8*>(&Bs[buf][R * 64 + ((q ^ (R & 7)) << 3)]);\
            }                                                                                       \
            _Pragma("unroll")                                                                       \
            for (int mi = 0; mi < 4; mi++)                                                          \
                _Pragma("unroll")                                                                   \
                for (int ni = 0; ni < 4; ni++)                                                      \
                    acc[mi][ni] = __builtin_amdgcn_mfma_f32_16x16x32_bf16(af[mi], bfv[ni],          \
                                                                          acc[mi][ni], 0, 0, 0);    \
        }                                                                                           \
    }

    STAGE(0, 0);
    __syncthreads();  // drain prologue stage
    int cur = 0;
    for (int k0 = 64; k0 < KDIM; k0 += 64) {
        STAGE(cur ^ 1, k0);   // async: overlaps with compute below
        COMPUTE(cur);
        __syncthreads();      // drains vmcnt (stage done) + syncs buffer swap
        cur ^= 1;
    }
    COMPUTE(cur);
#undef STAGE
#undef COMPUTE

    int orow = (lane >> 4) * 4;
    int ocol = lane & 15;
#pragma unroll
    for (int mi = 0; mi < 4; mi++) {
#pragma unroll
        for (int ni = 0; ni < 4; ni++) {
            int gr = m0 + wm + mi * 16 + orow;
            int gc = n0 + wn + ni * 16 + ocol;
            float bv = bias[gc];
#pragma unroll
            for (int j = 0; j < 4; j++) {
                float v = acc[mi][ni][j] + bv;
                size_t idx = (size_t)(gr + j) * NDIM + gc;
                if constexpr (EPI == 1) {
                    float sv = v / (1.0f + __expf(-v));
                    outb[idx] = (__bf16)sv;
                } else {
                    outf[idx] = v + yadd[idx];
                }
            }
        }
    }
}

// ---------------- launcher ----------------
extern "C" void kernel_launch(void* const* d_in, const int* in_sizes, int n_in,
                              void* d_out, int out_size, void* d_ws, size_t ws_size,
                              hipStream_t stream) {
    const float* x = (const float*)d_in[0];
    const float* hr0 = (const float*)d_in[1];
    const float* hi0 = (const float*)d_in[2];
    const float* pre = (const float*)d_in[3];
    const float* pim = (const float*)d_in[4];
    const float* pinr = (const float*)d_in[5];
    const float* pini = (const float*)d_in[6];
    const float* lng = (const float*)d_in[7];
    const float* lnb = (const float*)d_in[8];
    const float* w1 = (const float*)d_in[9];
    const float* b1 = (const float*)d_in[10];
    const float* w2 = (const float*)d_in[11];
    const float* b2 = (const float*)d_in[12];

    const size_t n = (size_t)BB * LL * DD;  // 8M elements
    float* outp = (float*)d_out;            // [0, 32MB): y then final out
    char* hidbase = (char*)d_out + n * 4;   // hidden region (>=32MB)
    float* hidp = (float*)hidbase;
    bool interleaved = (out_size >= (int)(3 * n));  // measured: false (hidden = real f32)

    // Small scratch in ws (4.375MB)
    char* ws = (char*)d_ws;
    float* xstats = (float*)ws;      ws += (size_t)BB * LL * 2 * 4;        // 128KB
    float* carry = (float*)ws;       ws += (size_t)BB * CHUNKS * DD * 8;   // 1MB
    float* carry_in = (float*)ws;    ws += (size_t)BB * CHUNKS * DD * 8;   // 1MB
    __bf16* w1t = (__bf16*)ws;       ws += (size_t)DD * DF * 2;            // 1MB
    __bf16* w2t = (__bf16*)ws;       ws += (size_t)DF * DD * 2;            // 1MB
    char* ws_big = ws;  // FFN staging if room
    const size_t SMALL = (size_t)(128 + 1024 + 1024 + 1024 + 1024) * 1024;
    const size_t NEED_FULL = SMALL + ((size_t)48 << 20);  // yn 16MB + h1 32MB
    const size_t NEED_HALF = SMALL + ((size_t)24 << 20);  // yn_h 8MB + h1_h 16MB

    // Common prefix
    k_wt<<<dim3((DD / 32) * (DF / 32), 2), 256, 0, stream>>>(w1, w2, w1t, w2t);
    k_xstats<<<(BB * LL) / 4, 256, 0, stream>>>(x, xstats);
    k_scan_partial<<<BB * CHUNKS, 512, 0, stream>>>(x, xstats, pre, pim, pinr, pini, lng, lnb, carry);
    k_chunk_scan<<<BB, 512, 0, stream>>>(hr0, hi0, pre, pim, carry, carry_in);

    if (!interleaved && ws_size >= NEED_FULL) {
        // Tier A: FFN staging fully in ws; fused y+hidden scan; single full-size FFN
        __bf16* yn = (__bf16*)ws_big;
        __bf16* h1 = (__bf16*)(ws_big + ((size_t)16 << 20));
        k_scan_out<3><<<BB * CHUNKS, 512, 0, stream>>>(x, xstats, pre, pim, pinr, pini, lng, lnb,
                                                       carry_in, outp, hidp);
        k_ynorm<<<(BB * LL) / 4, 256, 0, stream>>>(outp, lng, lnb, yn);
        k_gemm<DD, DF, 1><<<(BB * LL / 128) * (DF / 128), 256, 0, stream>>>(
            yn, w1t, b1, nullptr, nullptr, h1);
        k_gemm<DF, DD, 2><<<(BB * LL / 128) * (DD / 128), 256, 0, stream>>>(
            h1, w2t, b2, outp, outp, nullptr);
    } else if (!interleaved && ws_size >= NEED_HALF) {
        // Tier B: halved FFN staging in ws; fused y+hidden scan
        __bf16* yn_h = (__bf16*)ws_big;
        __bf16* h1_h = (__bf16*)(ws_big + ((size_t)8 << 20));
        k_scan_out<3><<<BB * CHUNKS, 512, 0, stream>>>(x, xstats, pre, pim, pinr, pini, lng, lnb,
                                                       carry_in, outp, hidp);
        for (int h = 0; h < 2; h++) {
            float* yh = outp + (size_t)h * HALF_ROWS * DD;
            k_ynorm<<<HALF_ROWS / 4, 256, 0, stream>>>(yh, lng, lnb, yn_h);
            k_gemm<DD, DF, 1><<<(HALF_ROWS / 128) * (DF / 128), 256, 0, stream>>>(
                yn_h, w1t, b1, nullptr, nullptr, h1_h);
            k_gemm<DF, DD, 2><<<(HALF_ROWS / 128) * (DD / 128), 256, 0, stream>>>(
                h1_h, w2t, b2, yh, yh, nullptr);
        }
    } else {
        // Tier C (proven fallback): stage FFN inside the hidden window, rewrite hidden last
        __bf16* yn_h = (__bf16*)hidbase;
        __bf16* h1_h = (__bf16*)(hidbase + ((size_t)8 << 20));
        k_scan_out<0><<<BB * CHUNKS, 512, 0, stream>>>(x, xstats, pre, pim, pinr, pini, lng, lnb,
                                                       carry_in, outp, nullptr);
        for (int h = 0; h < 2; h++) {
            float* yh = outp + (size_t)h * HALF_ROWS * DD;
            k_ynorm<<<HALF_ROWS / 4, 256, 0, stream>>>(yh, lng, lnb, yn_h);
            k_gemm<DD, DF, 1><<<(HALF_ROWS / 128) * (DF / 128), 256, 0, stream>>>(
                yn_h, w1t, b1, nullptr, nullptr, h1_h);
            k_gemm<DF, DD, 2><<<(HALF_ROWS / 128) * (DD / 128), 256, 0, stream>>>(
                h1_h, w2t, b2, yh, yh, nullptr);
        }
        if (interleaved) {
            k_scan_out<2><<<BB * CHUNKS, 512, 0, stream>>>(x, xstats, pre, pim, pinr, pini, lng, lnb,
                                                           carry_in, nullptr, hidp);
        } else {
            k_scan_out<1><<<BB * CHUNKS, 512, 0, stream>>>(x, xstats, pre, pim, pinr, pini, lng, lnb,
                                                           carry_in, nullptr, hidp);
        }
    }
}

// Round 10
// 115.597 us; speedup vs baseline: 1.0873x; 1.0873x over previous
//
#include <hip/hip_runtime.h>
#include <hip/hip_bf16.h>
#include <math.h>

#define BB 4
#define LL 4096
#define DD 512
#define DF 1024
#define CHUNKS 64
#define LC 64  // LL / CHUNKS
#define HALF_ROWS 8192

typedef __bf16 bf16x8 __attribute__((ext_vector_type(8)));
typedef float f32x4 __attribute__((ext_vector_type(4)));

// ---------------- phazor helper ----------------
__device__ inline void get_phazor(const float* __restrict__ pre, const float* __restrict__ pim,
                                  int d, float& ar, float& ai) {
    float pr = pre[d], pi = pim[d];
    float ab = sqrtf(pr * pr + pi * pi);
    float sc = expf(-ab) / ab;
    ar = pr * sc;
    ai = pi * sc;
}

// ---------------- kernel W: coalesced 32x32 tiled transpose f32 -> bf16 ----------------
__global__ __launch_bounds__(256) void k_wt(const float* __restrict__ w1, const float* __restrict__ w2,
                                            __bf16* __restrict__ w1t, __bf16* __restrict__ w2t) {
    __shared__ float tile[32][33];
    const float* src;
    __bf16* dst;
    int R, C;
    if (blockIdx.y == 0) { src = w1; dst = w1t; R = DD; C = DF; }
    else                 { src = w2; dst = w2t; R = DF; C = DD; }
    int ntx = C / 32;
    int c0 = (blockIdx.x % ntx) * 32, r0 = (blockIdx.x / ntx) * 32;
    int tx = threadIdx.x & 31, ty = threadIdx.x >> 5;  // ty in 0..7
#pragma unroll
    for (int i = 0; i < 32; i += 8)
        tile[ty + i][tx] = src[(size_t)(r0 + ty + i) * C + c0 + tx];
    __syncthreads();
#pragma unroll
    for (int i = 0; i < 32; i += 8)
        dst[(size_t)(c0 + ty + i) * R + r0 + tx] = (__bf16)tile[tx][ty + i];
}

// ---------------- kernel A: x row stats ----------------
__global__ __launch_bounds__(256) void k_xstats(const float* __restrict__ x, float* __restrict__ xstats) {
    int wave = threadIdx.x >> 6, lane = threadIdx.x & 63;
    size_t row = (size_t)blockIdx.x * 4 + wave;  // 16384 rows
    const float4* xr = reinterpret_cast<const float4*>(x + row * DD) + lane * 2;
    float4 a = xr[0], b = xr[1];
    float s = a.x + a.y + a.z + a.w + b.x + b.y + b.z + b.w;
    float q = a.x * a.x + a.y * a.y + a.z * a.z + a.w * a.w +
              b.x * b.x + b.y * b.y + b.z * b.z + b.w * b.w;
#pragma unroll
    for (int off = 32; off; off >>= 1) {
        s += __shfl_down(s, off);
        q += __shfl_down(q, off);
    }
    if (lane == 0) {
        float m = s * (1.0f / DD);
        float v = q * (1.0f / DD) - m * m;
        xstats[row * 2 + 0] = m;
        xstats[row * 2 + 1] = rsqrtf(v + 1e-5f);
    }
}

// ---------------- kernel B: per-chunk partial scan (zero init) ----------------
__global__ __launch_bounds__(512) void k_scan_partial(
    const float* __restrict__ x, const float* __restrict__ xstats,
    const float* __restrict__ pre, const float* __restrict__ pim,
    const float* __restrict__ pinr, const float* __restrict__ pini,
    const float* __restrict__ g, const float* __restrict__ bvec,
    float* __restrict__ carry) {
    int d = threadIdx.x;
    int c = blockIdx.x % CHUNKS, b = blockIdx.x / CHUNKS;
    float ar, ai;
    get_phazor(pre, pim, d, ar, ai);
    float pr = pinr[d], pi = pini[d];
    float gd = g[d], bd = bvec[d];
    float hr = 0.f, hi = 0.f;
    int l0 = c * LC;
    const float* xp = x + ((size_t)b * LL + l0) * DD + d;
    const float* st = xstats + ((size_t)b * LL + l0) * 2;
    for (int i = 0; i < LC; i++) {
        float m = st[2 * i], r = st[2 * i + 1];
        float xn = (xp[(size_t)i * DD] - m) * r * gd + bd;
        float ur = pr * xn, ui = pi * xn;
        float t = ar * hr - ai * hi + ur;
        hi = ar * hi + ai * hr + ui;
        hr = t;
    }
    size_t idx = ((size_t)blockIdx.x * DD + d) * 2;
    carry[idx] = hr;
    carry[idx + 1] = hi;
}

// ---------------- kernel C: cross-chunk scan ----------------
__global__ __launch_bounds__(512) void k_chunk_scan(
    const float* __restrict__ hr0, const float* __restrict__ hi0,
    const float* __restrict__ pre, const float* __restrict__ pim,
    const float* __restrict__ carry, float* __restrict__ carry_in) {
    int d = threadIdx.x, b = blockIdx.x;
    float ar, ai;
    get_phazor(pre, pim, d, ar, ai);
    float sr = ar, si = ai;  // a^64 via 6 squarings
#pragma unroll
    for (int i = 0; i < 6; i++) {
        float t = sr * sr - si * si;
        si = 2.f * sr * si;
        sr = t;
    }
    float cr = hr0[b * DD + d], ci = hi0[b * DD + d];
    for (int k = 0; k < CHUNKS; k++) {
        size_t idx = (((size_t)b * CHUNKS + k) * DD + d) * 2;
        carry_in[idx] = cr;
        carry_in[idx + 1] = ci;
        float tr = carry[idx], ti = carry[idx + 1];
        float t = sr * cr - si * ci + tr;
        ci = sr * ci + si * cr + ti;
        cr = t;
    }
}

// ---------------- kernel D: final scan.
// MODE 0: y only. MODE 1: hidden real only. MODE 2: hidden interleaved only. MODE 3: y + hidden real.
template <int MODE>
__global__ __launch_bounds__(512) void k_scan_out(
    const float* __restrict__ x, const float* __restrict__ xstats,
    const float* __restrict__ pre, const float* __restrict__ pim,
    const float* __restrict__ pinr, const float* __restrict__ pini,
    const float* __restrict__ g, const float* __restrict__ bvec,
    const float* __restrict__ carry_in,
    float* __restrict__ out_y, float* __restrict__ hid) {
    int d = threadIdx.x;
    int c = blockIdx.x % CHUNKS, b = blockIdx.x / CHUNKS;
    float ar, ai;
    get_phazor(pre, pim, d, ar, ai);
    float pr = pinr[d], pi = pini[d];
    float gd = g[d], bd = bvec[d];
    size_t cidx = ((size_t)blockIdx.x * DD + d) * 2;
    float hr = carry_in[cidx], hi = carry_in[cidx + 1];
    int l0 = c * LC;
    const float* xp = x + ((size_t)b * LL + l0) * DD + d;
    const float* st = xstats + ((size_t)b * LL + l0) * 2;
    for (int i = 0; i < LC; i++) {
        float m = st[2 * i], r = st[2 * i + 1];
        float xv = xp[(size_t)i * DD];
        float xn = (xv - m) * r * gd + bd;
        float ur = pr * xn, ui = pi * xn;
        float t = ar * hr - ai * hi + ur;
        hi = ar * hi + ai * hr + ui;
        hr = t;
        size_t row = (size_t)b * LL + l0 + i;
        if constexpr (MODE == 0) {
            out_y[row * DD + d] = hr + xv;
        } else if constexpr (MODE == 1) {
            hid[row * DD + d] = hr;
        } else if constexpr (MODE == 2) {
            reinterpret_cast<float2*>(hid)[row * DD + d] = make_float2(hr, hi);
        } else {
            out_y[row * DD + d] = hr + xv;
            hid[row * DD + d] = hr;
        }
    }
}

// ---------------- kernel E: y -> yn (bf16 normalized) ----------------
__global__ __launch_bounds__(256) void k_ynorm(const float* __restrict__ y,
                                               const float* __restrict__ g, const float* __restrict__ bvec,
                                               __bf16* __restrict__ yn) {
    int wave = threadIdx.x >> 6, lane = threadIdx.x & 63;
    size_t row = (size_t)blockIdx.x * 4 + wave;
    const float4* yr = reinterpret_cast<const float4*>(y + row * DD) + lane * 2;
    float4 a = yr[0], b = yr[1];
    float s = a.x + a.y + a.z + a.w + b.x + b.y + b.z + b.w;
    float q = a.x * a.x + a.y * a.y + a.z * a.z + a.w * a.w +
              b.x * b.x + b.y * b.y + b.z * b.z + b.w * b.w;
#pragma unroll
    for (int off = 32; off; off >>= 1) {
        s += __shfl_xor(s, off);
        q += __shfl_xor(q, off);
    }
    float m = s * (1.0f / DD);
    float r = rsqrtf(q * (1.0f / DD) - m * m + 1e-5f);
    int dbase = lane * 8;
    const float4* gp = reinterpret_cast<const float4*>(g + dbase);
    const float4* bp = reinterpret_cast<const float4*>(bvec + dbase);
    float4 g0 = gp[0], g1 = gp[1], b0 = bp[0], b1 = bp[1];
    bf16x8 o;
    o[0] = (__bf16)((a.x - m) * r * g0.x + b0.x);
    o[1] = (__bf16)((a.y - m) * r * g0.y + b0.y);
    o[2] = (__bf16)((a.z - m) * r * g0.z + b0.z);
    o[3] = (__bf16)((a.w - m) * r * g0.w + b0.w);
    o[4] = (__bf16)((b.x - m) * r * g1.x + b1.x);
    o[5] = (__bf16)((b.y - m) * r * g1.y + b1.y);
    o[6] = (__bf16)((b.z - m) * r * g1.z + b1.z);
    o[7] = (__bf16)((b.w - m) * r * g1.w + b1.w);
    *reinterpret_cast<bf16x8*>(yn + row * DD + dbase) = o;
}

// ---------------- GEMM: big-tile 2-phase double-buffer, 512 threads / 8 waves ----------------
// C[m][n] = A[m][:].Bt[n][:] ; EPI 1: out_bf16 = silu(acc+bias). EPI 2: out_f32 = acc+bias+yadd.
// Tile BM x BN, BK=64; waves 2(M) x 4(N); per-wave output (BM/2) x (BN/4).
// LDS 2 x ([BM][64] + [BN][64]) bf16; linear gload_lds dest; 16B-chunk col XOR (row&7)
// swizzle applied on global source AND ds_read (both-sides, rule 21).
template <int BM, int BN, int KDIM, int NDIM, int EPI>
__global__ __launch_bounds__(512) void k_gemm(
    const __bf16* __restrict__ A, const __bf16* __restrict__ Bt,
    const float* __restrict__ bias, const float* __restrict__ yadd,
    float* __restrict__ outf, __bf16* __restrict__ outb) {
    __shared__ __align__(16) __bf16 As[2][BM * 64];
    __shared__ __align__(16) __bf16 Bs[2][BN * 64];
    constexpr int NT = NDIM / BN;
    constexpr int MR = BM / 32;  // m-frags per wave (BM/2/16)
    constexpr int NR = BN / 64;  // n-frags per wave (BN/4/16)
    int nwg = gridDim.x;
    int bid = blockIdx.x;
    int swz = (bid & 7) * (nwg >> 3) + (bid >> 3);
    int m0 = (swz / NT) * BM;
    int n0 = (swz % NT) * BN;
    int tid = threadIdx.x;
    int wid = tid >> 6, lane = tid & 63;

    f32x4 acc[MR][NR] = {};

    int wm = (wid >> 2) * (BM / 2), wn = (wid & 3) * (BN / 4);
    int fr = lane & 15;         // fragment row within 16
    int qbase = lane >> 4;      // 16B-chunk quarter within first 4 chunks

    auto stage = [&](int buf, int k0) {
#pragma unroll
        for (int i = 0; i < BM / 64; i++) {
            int c = tid + i * 512;
            int row = c >> 3, kq = c & 7;
            int kqg = kq ^ (row & 7);
            const __bf16* ga = A + (size_t)(m0 + row) * KDIM + k0 + kqg * 8;
            __bf16* la = &As[buf][(size_t)(i * 512 + wid * 64) * 8];
            __builtin_amdgcn_global_load_lds((const __attribute__((address_space(1))) unsigned int*)ga,
                                             (__attribute__((address_space(3))) unsigned int*)la, 16, 0, 0);
        }
#pragma unroll
        for (int i = 0; i < BN / 64; i++) {
            int c = tid + i * 512;
            int row = c >> 3, kq = c & 7;
            int kqg = kq ^ (row & 7);
            const __bf16* gb = Bt + (size_t)(n0 + row) * KDIM + k0 + kqg * 8;
            __bf16* lb = &Bs[buf][(size_t)(i * 512 + wid * 64) * 8];
            __builtin_amdgcn_global_load_lds((const __attribute__((address_space(1))) unsigned int*)gb,
                                             (__attribute__((address_space(3))) unsigned int*)lb, 16, 0, 0);
        }
    };

    auto compute = [&](int buf) {
#pragma unroll
        for (int ks = 0; ks < 2; ks++) {
            int q = ks * 4 + qbase;
            bf16x8 af[MR], bfv[NR];
#pragma unroll
            for (int mi = 0; mi < MR; mi++) {
                int R = wm + mi * 16 + fr;
                af[mi] = *reinterpret_cast<const bf16x8*>(&As[buf][R * 64 + ((q ^ (R & 7)) << 3)]);
            }
#pragma unroll
            for (int ni = 0; ni < NR; ni++) {
                int R = wn + ni * 16 + fr;
                bfv[ni] = *reinterpret_cast<const bf16x8*>(&Bs[buf][R * 64 + ((q ^ (R & 7)) << 3)]);
            }
#pragma unroll
            for (int mi = 0; mi < MR; mi++)
#pragma unroll
                for (int ni = 0; ni < NR; ni++)
                    acc[mi][ni] = __builtin_amdgcn_mfma_f32_16x16x32_bf16(af[mi], bfv[ni],
                                                                          acc[mi][ni], 0, 0, 0);
        }
    };

    stage(0, 0);
    __syncthreads();  // drain prologue stage
    int cur = 0;
    for (int k0 = 64; k0 < KDIM; k0 += 64) {
        stage(cur ^ 1, k0);   // async: overlaps with compute below
        compute(cur);
        __syncthreads();      // drains vmcnt (stage done) + buffer swap
        cur ^= 1;
    }
    compute(cur);

    int orow = (lane >> 4) * 4;
    int ocol = lane & 15;
#pragma unroll
    for (int mi = 0; mi < MR; mi++) {
#pragma unroll
        for (int ni = 0; ni < NR; ni++) {
            int gr = m0 + wm + mi * 16 + orow;
            int gc = n0 + wn + ni * 16 + ocol;
            float bv = bias[gc];
#pragma unroll
            for (int j = 0; j < 4; j++) {
                float v = acc[mi][ni][j] + bv;
                size_t idx = (size_t)(gr + j) * NDIM + gc;
                if constexpr (EPI == 1) {
                    float sv = v / (1.0f + __expf(-v));
                    outb[idx] = (__bf16)sv;
                } else {
                    outf[idx] = v + yadd[idx];
                }
            }
        }
    }
}

// ---------------- launcher ----------------
extern "C" void kernel_launch(void* const* d_in, const int* in_sizes, int n_in,
                              void* d_out, int out_size, void* d_ws, size_t ws_size,
                              hipStream_t stream) {
    const float* x = (const float*)d_in[0];
    const float* hr0 = (const float*)d_in[1];
    const float* hi0 = (const float*)d_in[2];
    const float* pre = (const float*)d_in[3];
    const float* pim = (const float*)d_in[4];
    const float* pinr = (const float*)d_in[5];
    const float* pini = (const float*)d_in[6];
    const float* lng = (const float*)d_in[7];
    const float* lnb = (const float*)d_in[8];
    const float* w1 = (const float*)d_in[9];
    const float* b1 = (const float*)d_in[10];
    const float* w2 = (const float*)d_in[11];
    const float* b2 = (const float*)d_in[12];

    const size_t n = (size_t)BB * LL * DD;  // 8M elements
    float* outp = (float*)d_out;            // [0, 32MB): y then final out
    char* hidbase = (char*)d_out + n * 4;   // hidden region (>=32MB)
    float* hidp = (float*)hidbase;
    bool interleaved = (out_size >= (int)(3 * n));  // measured: false (hidden = real f32)

    // Small scratch in ws (4.375MB)
    char* ws = (char*)d_ws;
    float* xstats = (float*)ws;      ws += (size_t)BB * LL * 2 * 4;        // 128KB
    float* carry = (float*)ws;       ws += (size_t)BB * CHUNKS * DD * 8;   // 1MB
    float* carry_in = (float*)ws;    ws += (size_t)BB * CHUNKS * DD * 8;   // 1MB
    __bf16* w1t = (__bf16*)ws;       ws += (size_t)DD * DF * 2;            // 1MB
    __bf16* w2t = (__bf16*)ws;       ws += (size_t)DF * DD * 2;            // 1MB
    char* ws_big = ws;  // FFN staging if room
    const size_t SMALL = (size_t)(128 + 1024 + 1024 + 1024 + 1024) * 1024;
    const size_t NEED_FULL = SMALL + ((size_t)48 << 20);  // yn 16MB + h1 32MB
    const size_t NEED_HALF = SMALL + ((size_t)24 << 20);  // yn_h 8MB + h1_h 16MB

    // Common prefix
    k_wt<<<dim3((DD / 32) * (DF / 32), 2), 256, 0, stream>>>(w1, w2, w1t, w2t);
    k_xstats<<<(BB * LL) / 4, 256, 0, stream>>>(x, xstats);
    k_scan_partial<<<BB * CHUNKS, 512, 0, stream>>>(x, xstats, pre, pim, pinr, pini, lng, lnb, carry);
    k_chunk_scan<<<BB, 512, 0, stream>>>(hr0, hi0, pre, pim, carry, carry_in);

    if (!interleaved && ws_size >= NEED_FULL) {
        // Tier A: FFN staging fully in ws; fused y+hidden scan; single full-size FFN
        __bf16* yn = (__bf16*)ws_big;
        __bf16* h1 = (__bf16*)(ws_big + ((size_t)16 << 20));
        k_scan_out<3><<<BB * CHUNKS, 512, 0, stream>>>(x, xstats, pre, pim, pinr, pini, lng, lnb,
                                                       carry_in, outp, hidp);
        k_ynorm<<<(BB * LL) / 4, 256, 0, stream>>>(outp, lng, lnb, yn);
        k_gemm<256, 256, DD, DF, 1><<<(BB * LL / 256) * (DF / 256), 512, 0, stream>>>(
            yn, w1t, b1, nullptr, nullptr, h1);
        k_gemm<128, 256, DF, DD, 2><<<(BB * LL / 128) * (DD / 256), 512, 0, stream>>>(
            h1, w2t, b2, outp, outp, nullptr);
    } else if (!interleaved && ws_size >= NEED_HALF) {
        // Tier B: halved FFN staging in ws; fused y+hidden scan
        __bf16* yn_h = (__bf16*)ws_big;
        __bf16* h1_h = (__bf16*)(ws_big + ((size_t)8 << 20));
        k_scan_out<3><<<BB * CHUNKS, 512, 0, stream>>>(x, xstats, pre, pim, pinr, pini, lng, lnb,
                                                       carry_in, outp, hidp);
        for (int h = 0; h < 2; h++) {
            float* yh = outp + (size_t)h * HALF_ROWS * DD;
            k_ynorm<<<HALF_ROWS / 4, 256, 0, stream>>>(yh, lng, lnb, yn_h);
            k_gemm<256, 256, DD, DF, 1><<<(HALF_ROWS / 256) * (DF / 256), 512, 0, stream>>>(
                yn_h, w1t, b1, nullptr, nullptr, h1_h);
            k_gemm<128, 256, DF, DD, 2><<<(HALF_ROWS / 128) * (DD / 256), 512, 0, stream>>>(
                h1_h, w2t, b2, yh, yh, nullptr);
        }
    } else {
        // Tier C (proven fallback): stage FFN inside the hidden window, rewrite hidden last
        __bf16* yn_h = (__bf16*)hidbase;
        __bf16* h1_h = (__bf16*)(hidbase + ((size_t)8 << 20));
        k_scan_out<0><<<BB * CHUNKS, 512, 0, stream>>>(x, xstats, pre, pim, pinr, pini, lng, lnb,
                                                       carry_in, outp, nullptr);
        for (int h = 0; h < 2; h++) {
            float* yh = outp + (size_t)h * HALF_ROWS * DD;
            k_ynorm<<<HALF_ROWS / 4, 256, 0, stream>>>(yh, lng, lnb, yn_h);
            k_gemm<256, 256, DD, DF, 1><<<(HALF_ROWS / 256) * (DF / 256), 512, 0, stream>>>(
                yn_h, w1t, b1, nullptr, nullptr, h1_h);
            k_gemm<128, 256, DF, DD, 2><<<(HALF_ROWS / 128) * (DD / 256), 512, 0, stream>>>(
                h1_h, w2t, b2, yh, yh, nullptr);
        }
        if (interleaved) {
            k_scan_out<2><<<BB * CHUNKS, 512, 0, stream>>>(x, xstats, pre, pim, pinr, pini, lng, lnb,
                                                           carry_in, nullptr, hidp);
        } else {
            k_scan_out<1><<<BB * CHUNKS, 512, 0, stream>>>(x, xstats, pre, pim, pinr, pini, lng, lnb,
                                                           carry_in, nullptr, hidp);
        }
    }
}

// Round 11
// 113.451 us; speedup vs baseline: 1.1079x; 1.0189x over previous
//
#include <hip/hip_runtime.h>
#include <hip/hip_bf16.h>
#include <math.h>

#define BB 4
#define LL 4096
#define DD 512
#define DF 1024
#define CHUNKS 64
#define LC 64  // LL / CHUNKS
#define HALF_ROWS 8192

typedef __bf16 bf16x8 __attribute__((ext_vector_type(8)));
typedef float f32x4 __attribute__((ext_vector_type(4)));

// ---------------- phazor helper ----------------
__device__ inline void get_phazor(const float* __restrict__ pre, const float* __restrict__ pim,
                                  int d, float& ar, float& ai) {
    float pr = pre[d], pi = pim[d];
    float ab = sqrtf(pr * pr + pi * pi);
    float sc = expf(-ab) / ab;
    ar = pr * sc;
    ai = pi * sc;
}

// ---------------- kernel W: coalesced 32x32 tiled transpose f32 -> bf16 ----------------
__global__ __launch_bounds__(256) void k_wt(const float* __restrict__ w1, const float* __restrict__ w2,
                                            __bf16* __restrict__ w1t, __bf16* __restrict__ w2t) {
    __shared__ float tile[32][33];
    const float* src;
    __bf16* dst;
    int R, C;
    if (blockIdx.y == 0) { src = w1; dst = w1t; R = DD; C = DF; }
    else                 { src = w2; dst = w2t; R = DF; C = DD; }
    int ntx = C / 32;
    int c0 = (blockIdx.x % ntx) * 32, r0 = (blockIdx.x / ntx) * 32;
    int tx = threadIdx.x & 31, ty = threadIdx.x >> 5;  // ty in 0..7
#pragma unroll
    for (int i = 0; i < 32; i += 8)
        tile[ty + i][tx] = src[(size_t)(r0 + ty + i) * C + c0 + tx];
    __syncthreads();
#pragma unroll
    for (int i = 0; i < 32; i += 8)
        dst[(size_t)(c0 + ty + i) * R + r0 + tx] = (__bf16)tile[tx][ty + i];
}

// ---------------- kernel A: x row stats ----------------
__global__ __launch_bounds__(256) void k_xstats(const float* __restrict__ x, float* __restrict__ xstats) {
    int wave = threadIdx.x >> 6, lane = threadIdx.x & 63;
    size_t row = (size_t)blockIdx.x * 4 + wave;  // 16384 rows
    const float4* xr = reinterpret_cast<const float4*>(x + row * DD) + lane * 2;
    float4 a = xr[0], b = xr[1];
    float s = a.x + a.y + a.z + a.w + b.x + b.y + b.z + b.w;
    float q = a.x * a.x + a.y * a.y + a.z * a.z + a.w * a.w +
              b.x * b.x + b.y * b.y + b.z * b.z + b.w * b.w;
#pragma unroll
    for (int off = 32; off; off >>= 1) {
        s += __shfl_down(s, off);
        q += __shfl_down(q, off);
    }
    if (lane == 0) {
        float m = s * (1.0f / DD);
        float v = q * (1.0f / DD) - m * m;
        xstats[row * 2 + 0] = m;
        xstats[row * 2 + 1] = rsqrtf(v + 1e-5f);
    }
}

// ---------------- kernel B: per-chunk partial scan (zero init) ----------------
__global__ __launch_bounds__(512) void k_scan_partial(
    const float* __restrict__ x, const float* __restrict__ xstats,
    const float* __restrict__ pre, const float* __restrict__ pim,
    const float* __restrict__ pinr, const float* __restrict__ pini,
    const float* __restrict__ g, const float* __restrict__ bvec,
    float* __restrict__ carry) {
    int d = threadIdx.x;
    int c = blockIdx.x % CHUNKS, b = blockIdx.x / CHUNKS;
    float ar, ai;
    get_phazor(pre, pim, d, ar, ai);
    float pr = pinr[d], pi = pini[d];
    float gd = g[d], bd = bvec[d];
    float hr = 0.f, hi = 0.f;
    int l0 = c * LC;
    const float* xp = x + ((size_t)b * LL + l0) * DD + d;
    const float* st = xstats + ((size_t)b * LL + l0) * 2;
    for (int i = 0; i < LC; i++) {
        float m = st[2 * i], r = st[2 * i + 1];
        float xn = (xp[(size_t)i * DD] - m) * r * gd + bd;
        float ur = pr * xn, ui = pi * xn;
        float t = ar * hr - ai * hi + ur;
        hi = ar * hi + ai * hr + ui;
        hr = t;
    }
    size_t idx = ((size_t)blockIdx.x * DD + d) * 2;
    carry[idx] = hr;
    carry[idx + 1] = hi;
}

// ---------------- kernel C: cross-chunk scan ----------------
__global__ __launch_bounds__(512) void k_chunk_scan(
    const float* __restrict__ hr0, const float* __restrict__ hi0,
    const float* __restrict__ pre, const float* __restrict__ pim,
    const float* __restrict__ carry, float* __restrict__ carry_in) {
    int d = threadIdx.x, b = blockIdx.x;
    float ar, ai;
    get_phazor(pre, pim, d, ar, ai);
    float sr = ar, si = ai;  // a^64 via 6 squarings
#pragma unroll
    for (int i = 0; i < 6; i++) {
        float t = sr * sr - si * si;
        si = 2.f * sr * si;
        sr = t;
    }
    float cr = hr0[b * DD + d], ci = hi0[b * DD + d];
    for (int k = 0; k < CHUNKS; k++) {
        size_t idx = (((size_t)b * CHUNKS + k) * DD + d) * 2;
        carry_in[idx] = cr;
        carry_in[idx + 1] = ci;
        float tr = carry[idx], ti = carry[idx + 1];
        float t = sr * cr - si * ci + tr;
        ci = sr * ci + si * cr + ti;
        cr = t;
    }
}

// ---------------- kernel D: final scan.
// MODE 0: y only. MODE 1: hidden real only. MODE 2: hidden interleaved only. MODE 3: y + hidden real.
template <int MODE>
__global__ __launch_bounds__(512) void k_scan_out(
    const float* __restrict__ x, const float* __restrict__ xstats,
    const float* __restrict__ pre, const float* __restrict__ pim,
    const float* __restrict__ pinr, const float* __restrict__ pini,
    const float* __restrict__ g, const float* __restrict__ bvec,
    const float* __restrict__ carry_in,
    float* __restrict__ out_y, float* __restrict__ hid) {
    int d = threadIdx.x;
    int c = blockIdx.x % CHUNKS, b = blockIdx.x / CHUNKS;
    float ar, ai;
    get_phazor(pre, pim, d, ar, ai);
    float pr = pinr[d], pi = pini[d];
    float gd = g[d], bd = bvec[d];
    size_t cidx = ((size_t)blockIdx.x * DD + d) * 2;
    float hr = carry_in[cidx], hi = carry_in[cidx + 1];
    int l0 = c * LC;
    const float* xp = x + ((size_t)b * LL + l0) * DD + d;
    const float* st = xstats + ((size_t)b * LL + l0) * 2;
    for (int i = 0; i < LC; i++) {
        float m = st[2 * i], r = st[2 * i + 1];
        float xv = xp[(size_t)i * DD];
        float xn = (xv - m) * r * gd + bd;
        float ur = pr * xn, ui = pi * xn;
        float t = ar * hr - ai * hi + ur;
        hi = ar * hi + ai * hr + ui;
        hr = t;
        size_t row = (size_t)b * LL + l0 + i;
        if constexpr (MODE == 0) {
            out_y[row * DD + d] = hr + xv;
        } else if constexpr (MODE == 1) {
            hid[row * DD + d] = hr;
        } else if constexpr (MODE == 2) {
            reinterpret_cast<float2*>(hid)[row * DD + d] = make_float2(hr, hi);
        } else {
            out_y[row * DD + d] = hr + xv;
            hid[row * DD + d] = hr;
        }
    }
}

// ---------------- kernel E: y -> yn (bf16 normalized) ----------------
__global__ __launch_bounds__(256) void k_ynorm(const float* __restrict__ y,
                                               const float* __restrict__ g, const float* __restrict__ bvec,
                                               __bf16* __restrict__ yn) {
    int wave = threadIdx.x >> 6, lane = threadIdx.x & 63;
    size_t row = (size_t)blockIdx.x * 4 + wave;
    const float4* yr = reinterpret_cast<const float4*>(y + row * DD) + lane * 2;
    float4 a = yr[0], b = yr[1];
    float s = a.x + a.y + a.z + a.w + b.x + b.y + b.z + b.w;
    float q = a.x * a.x + a.y * a.y + a.z * a.z + a.w * a.w +
              b.x * b.x + b.y * b.y + b.z * b.z + b.w * b.w;
#pragma unroll
    for (int off = 32; off; off >>= 1) {
        s += __shfl_xor(s, off);
        q += __shfl_xor(q, off);
    }
    float m = s * (1.0f / DD);
    float r = rsqrtf(q * (1.0f / DD) - m * m + 1e-5f);
    int dbase = lane * 8;
    const float4* gp = reinterpret_cast<const float4*>(g + dbase);
    const float4* bp = reinterpret_cast<const float4*>(bvec + dbase);
    float4 g0 = gp[0], g1 = gp[1], b0 = bp[0], b1 = bp[1];
    bf16x8 o;
    o[0] = (__bf16)((a.x - m) * r * g0.x + b0.x);
    o[1] = (__bf16)((a.y - m) * r * g0.y + b0.y);
    o[2] = (__bf16)((a.z - m) * r * g0.z + b0.z);
    o[3] = (__bf16)((a.w - m) * r * g0.w + b0.w);
    o[4] = (__bf16)((b.x - m) * r * g1.x + b1.x);
    o[5] = (__bf16)((b.y - m) * r * g1.y + b1.y);
    o[6] = (__bf16)((b.z - m) * r * g1.z + b1.z);
    o[7] = (__bf16)((b.w - m) * r * g1.w + b1.w);
    *reinterpret_cast<bf16x8*>(yn + row * DD + dbase) = o;
}

// ---------------- GEMM: big-tile pipeline with COUNTED vmcnt (loads fly across barriers) ----
// C[m][n] = A[m][:].Bt[n][:] ; EPI 1: out_bf16 = silu(acc+bias). EPI 2: out_f32 = acc+bias+yadd.
// Tile BM x BN, BK=64; 512 thr / 8 waves (2M x 4N); per-wave (BM/2) x (BN/4).
// Double-buffered LDS; per K-step: issue next-tile global_load_lds (L=BM/64+BN/64 per thread),
// then s_waitcnt vmcnt(L) (oldest = current tile done; next tile stays in flight), raw
// s_barrier, MFMA (setprio 1), raw s_barrier. NO vmcnt(0) in the main loop (T4).
// 16B-chunk col XOR (row&7) swizzle on global source AND ds_read (both-sides, rule 21).
template <int BM, int BN, int KDIM, int NDIM, int EPI>
__global__ __launch_bounds__(512) void k_gemm(
    const __bf16* __restrict__ A, const __bf16* __restrict__ Bt,
    const float* __restrict__ bias, const float* __restrict__ yadd,
    float* __restrict__ outf, __bf16* __restrict__ outb) {
    __shared__ __align__(16) __bf16 As[2][BM * 64];
    __shared__ __align__(16) __bf16 Bs[2][BN * 64];
    constexpr int NT = NDIM / BN;
    constexpr int MR = BM / 32;           // m-frags per wave
    constexpr int NR = BN / 64;           // n-frags per wave
    constexpr int LPT = BM / 64 + BN / 64;  // global_load_lds per thread per tile
    int nwg = gridDim.x;
    int bid = blockIdx.x;
    int swz = (bid & 7) * (nwg >> 3) + (bid >> 3);
    int m0 = (swz / NT) * BM;
    int n0 = (swz % NT) * BN;
    int tid = threadIdx.x;
    int wid = tid >> 6, lane = tid & 63;

    f32x4 acc[MR][NR] = {};

    int wm = (wid >> 2) * (BM / 2), wn = (wid & 3) * (BN / 4);
    int fr = lane & 15;         // fragment row within 16
    int qbase = lane >> 4;      // 16B-chunk quarter

    auto stage = [&](int buf, int k0) {
#pragma unroll
        for (int i = 0; i < BM / 64; i++) {
            int c = tid + i * 512;
            int row = c >> 3, kq = c & 7;
            int kqg = kq ^ (row & 7);
            const __bf16* ga = A + (size_t)(m0 + row) * KDIM + k0 + kqg * 8;
            __bf16* la = &As[buf][(size_t)(i * 512 + wid * 64) * 8];
            __builtin_amdgcn_global_load_lds((const __attribute__((address_space(1))) unsigned int*)ga,
                                             (__attribute__((address_space(3))) unsigned int*)la, 16, 0, 0);
        }
#pragma unroll
        for (int i = 0; i < BN / 64; i++) {
            int c = tid + i * 512;
            int row = c >> 3, kq = c & 7;
            int kqg = kq ^ (row & 7);
            const __bf16* gb = Bt + (size_t)(n0 + row) * KDIM + k0 + kqg * 8;
            __bf16* lb = &Bs[buf][(size_t)(i * 512 + wid * 64) * 8];
            __builtin_amdgcn_global_load_lds((const __attribute__((address_space(1))) unsigned int*)gb,
                                             (__attribute__((address_space(3))) unsigned int*)lb, 16, 0, 0);
        }
    };

    auto compute = [&](int buf) {
#pragma unroll
        for (int ks = 0; ks < 2; ks++) {
            int q = ks * 4 + qbase;
            bf16x8 af[MR], bfv[NR];
#pragma unroll
            for (int mi = 0; mi < MR; mi++) {
                int R = wm + mi * 16 + fr;
                af[mi] = *reinterpret_cast<const bf16x8*>(&As[buf][R * 64 + ((q ^ (R & 7)) << 3)]);
            }
#pragma unroll
            for (int ni = 0; ni < NR; ni++) {
                int R = wn + ni * 16 + fr;
                bfv[ni] = *reinterpret_cast<const bf16x8*>(&Bs[buf][R * 64 + ((q ^ (R & 7)) << 3)]);
            }
            __builtin_amdgcn_s_setprio(1);
#pragma unroll
            for (int mi = 0; mi < MR; mi++)
#pragma unroll
                for (int ni = 0; ni < NR; ni++)
                    acc[mi][ni] = __builtin_amdgcn_mfma_f32_16x16x32_bf16(af[mi], bfv[ni],
                                                                          acc[mi][ni], 0, 0, 0);
            __builtin_amdgcn_s_setprio(0);
        }
    };

    stage(0, 0);
    int cur = 0;
    for (int k0 = 64; k0 < KDIM; k0 += 64) {
        stage(cur ^ 1, k0);  // issue next tile: stays IN FLIGHT across the barriers below
        // wait only for the OLDEST loads (current tile); LPT newest remain outstanding
        asm volatile("s_waitcnt vmcnt(%0)" ::"i"(LPT) : "memory");
        __builtin_amdgcn_s_barrier();
        compute(cur);
        __builtin_amdgcn_s_barrier();  // protect buf[cur] before next stage overwrites it
        cur ^= 1;
    }
    asm volatile("s_waitcnt vmcnt(0)" ::: "memory");
    __builtin_amdgcn_s_barrier();
    compute(cur);

    int orow = (lane >> 4) * 4;
    int ocol = lane & 15;
#pragma unroll
    for (int mi = 0; mi < MR; mi++) {
#pragma unroll
        for (int ni = 0; ni < NR; ni++) {
            int gr = m0 + wm + mi * 16 + orow;
            int gc = n0 + wn + ni * 16 + ocol;
            float bv = bias[gc];
#pragma unroll
            for (int j = 0; j < 4; j++) {
                float v = acc[mi][ni][j] + bv;
                size_t idx = (size_t)(gr + j) * NDIM + gc;
                if constexpr (EPI == 1) {
                    float sv = v / (1.0f + __expf(-v));
                    outb[idx] = (__bf16)sv;
                } else {
                    outf[idx] = v + yadd[idx];
                }
            }
        }
    }
}

// ---------------- launcher ----------------
extern "C" void kernel_launch(void* const* d_in, const int* in_sizes, int n_in,
                              void* d_out, int out_size, void* d_ws, size_t ws_size,
                              hipStream_t stream) {
    const float* x = (const float*)d_in[0];
    const float* hr0 = (const float*)d_in[1];
    const float* hi0 = (const float*)d_in[2];
    const float* pre = (const float*)d_in[3];
    const float* pim = (const float*)d_in[4];
    const float* pinr = (const float*)d_in[5];
    const float* pini = (const float*)d_in[6];
    const float* lng = (const float*)d_in[7];
    const float* lnb = (const float*)d_in[8];
    const float* w1 = (const float*)d_in[9];
    const float* b1 = (const float*)d_in[10];
    const float* w2 = (const float*)d_in[11];
    const float* b2 = (const float*)d_in[12];

    const size_t n = (size_t)BB * LL * DD;  // 8M elements
    float* outp = (float*)d_out;            // [0, 32MB): y then final out
    char* hidbase = (char*)d_out + n * 4;   // hidden region (>=32MB)
    float* hidp = (float*)hidbase;
    bool interleaved = (out_size >= (int)(3 * n));  // measured: false (hidden = real f32)

    // Small scratch in ws (4.375MB)
    char* ws = (char*)d_ws;
    float* xstats = (float*)ws;      ws += (size_t)BB * LL * 2 * 4;        // 128KB
    float* carry = (float*)ws;       ws += (size_t)BB * CHUNKS * DD * 8;   // 1MB
    float* carry_in = (float*)ws;    ws += (size_t)BB * CHUNKS * DD * 8;   // 1MB
    __bf16* w1t = (__bf16*)ws;       ws += (size_t)DD * DF * 2;            // 1MB
    __bf16* w2t = (__bf16*)ws;       ws += (size_t)DF * DD * 2;            // 1MB
    char* ws_big = ws;  // FFN staging if room
    const size_t SMALL = (size_t)(128 + 1024 + 1024 + 1024 + 1024) * 1024;
    const size_t NEED_FULL = SMALL + ((size_t)48 << 20);  // yn 16MB + h1 32MB
    const size_t NEED_HALF = SMALL + ((size_t)24 << 20);  // yn_h 8MB + h1_h 16MB

    // Common prefix
    k_wt<<<dim3((DD / 32) * (DF / 32), 2), 256, 0, stream>>>(w1, w2, w1t, w2t);
    k_xstats<<<(BB * LL) / 4, 256, 0, stream>>>(x, xstats);
    k_scan_partial<<<BB * CHUNKS, 512, 0, stream>>>(x, xstats, pre, pim, pinr, pini, lng, lnb, carry);
    k_chunk_scan<<<BB, 512, 0, stream>>>(hr0, hi0, pre, pim, carry, carry_in);

    if (!interleaved && ws_size >= NEED_FULL) {
        // Tier A: FFN staging fully in ws; fused y+hidden scan; single full-size FFN
        __bf16* yn = (__bf16*)ws_big;
        __bf16* h1 = (__bf16*)(ws_big + ((size_t)16 << 20));
        k_scan_out<3><<<BB * CHUNKS, 512, 0, stream>>>(x, xstats, pre, pim, pinr, pini, lng, lnb,
                                                       carry_in, outp, hidp);
        k_ynorm<<<(BB * LL) / 4, 256, 0, stream>>>(outp, lng, lnb, yn);
        k_gemm<256, 256, DD, DF, 1><<<(BB * LL / 256) * (DF / 256), 512, 0, stream>>>(
            yn, w1t, b1, nullptr, nullptr, h1);
        k_gemm<128, 256, DF, DD, 2><<<(BB * LL / 128) * (DD / 256), 512, 0, stream>>>(
            h1, w2t, b2, outp, outp, nullptr);
    } else if (!interleaved && ws_size >= NEED_HALF) {
        // Tier B: halved FFN staging in ws; fused y+hidden scan
        __bf16* yn_h = (__bf16*)ws_big;
        __bf16* h1_h = (__bf16*)(ws_big + ((size_t)8 << 20));
        k_scan_out<3><<<BB * CHUNKS, 512, 0, stream>>>(x, xstats, pre, pim, pinr, pini, lng, lnb,
                                                       carry_in, outp, hidp);
        for (int h = 0; h < 2; h++) {
            float* yh = outp + (size_t)h * HALF_ROWS * DD;
            k_ynorm<<<HALF_ROWS / 4, 256, 0, stream>>>(yh, lng, lnb, yn_h);
            k_gemm<256, 256, DD, DF, 1><<<(HALF_ROWS / 256) * (DF / 256), 512, 0, stream>>>(
                yn_h, w1t, b1, nullptr, nullptr, h1_h);
            k_gemm<128, 256, DF, DD, 2><<<(HALF_ROWS / 128) * (DD / 256), 512, 0, stream>>>(
                h1_h, w2t, b2, yh, yh, nullptr);
        }
    } else {
        // Tier C (proven fallback): stage FFN inside the hidden window, rewrite hidden last
        __bf16* yn_h = (__bf16*)hidbase;
        __bf16* h1_h = (__bf16*)(hidbase + ((size_t)8 << 20));
        k_scan_out<0><<<BB * CHUNKS, 512, 0, stream>>>(x, xstats, pre, pim, pinr, pini, lng, lnb,
                                                       carry_in, outp, nullptr);
        for (int h = 0; h < 2; h++) {
            float* yh = outp + (size_t)h * HALF_ROWS * DD;
            k_ynorm<<<HALF_ROWS / 4, 256, 0, stream>>>(yh, lng, lnb, yn_h);
            k_gemm<256, 256, DD, DF, 1><<<(HALF_ROWS / 256) * (DF / 256), 512, 0, stream>>>(
                yn_h, w1t, b1, nullptr, nullptr, h1_h);
            k_gemm<128, 256, DF, DD, 2><<<(HALF_ROWS / 128) * (DD / 256), 512, 0, stream>>>(
                h1_h, w2t, b2, yh, yh, nullptr);
        }
        if (interleaved) {
            k_scan_out<2><<<BB * CHUNKS, 512, 0, stream>>>(x, xstats, pre, pim, pinr, pini, lng, lnb,
                                                           carry_in, nullptr, hidp);
        } else {
            k_scan_out<1><<<BB * CHUNKS, 512, 0, stream>>>(x, xstats, pre, pim, pinr, pini, lng, lnb,
                                                           carry_in, nullptr, hidp);
        }
    }
}